// Round 5
// baseline (261.926 us; speedup 1.0000x reference)
//
#include <hip/hip_runtime.h>
#include <hip/hip_bf16.h>

// JointNet: logp = log_softmax(tanh(enc@We + b_e (+) dec@Wd + b_d) @ Wfc + b_fc), masked.
// B=4 T=256 U=64 V=1024 F=1024 K_proj=512.
// R4 verdict: BM=64/BN=1024 forced (in-block softmax); acc=128 AGPR pins 2 waves/SIMD,
// 1 block/CU. Latency-bound on per-mstep B loads (L2 ~300cy, 2 waves can't hide).
// R5: m201-style B-feed — B chunks (64KB = 4 k8-slices) via global_load_lds into
// double-buffered LDS, issued at iter top / consumed next iter (1 iter of flight),
// vmcnt(0) only at iter end just before s_barrier (publish). A = tanh(pe+pd) reg-staged
// issue-early(even iter)/commit-late(odd iter) into XOR-swizzled LDS. setprio on MFMA.

#define TT 256
#define UU 64
#define VV 1024
#define FF 1024
#define DK 512

typedef __bf16 bf16x8 __attribute__((ext_vector_type(8)));
typedef float  f32x16 __attribute__((ext_vector_type(16)));

__device__ __forceinline__ float fast_tanh(float x) {
  float ax = __builtin_fabsf(x);
  float e  = __expf(-2.0f * ax);
  float r  = (1.0f - e) * __builtin_amdgcn_rcpf(1.0f + e);
  return __builtin_copysignf(r, x);
}

// ---------------- pack: W fp32 [K][1024] -> bf16 [K/8][1024][8] ----------------
__global__ __launch_bounds__(256)
void pack_w(const float* __restrict__ Wfc, const float* __restrict__ Wenc,
            const float* __restrict__ Wdec,
            __bf16* __restrict__ Pfc, __bf16* __restrict__ Pen, __bf16* __restrict__ Pde)
{
  int bi = blockIdx.x;
  const float* W; __bf16* P; int base;
  if (bi < 512)      { W = Wfc;  P = Pfc; base = bi; }
  else if (bi < 768) { W = Wenc; P = Pen; base = bi - 512; }
  else               { W = Wdec; P = Pde; base = bi - 768; }
  int idx = base * 256 + threadIdx.x;     // idx = k8*1024 + v
  int k8 = idx >> 10, v = idx & 1023;
  bf16x8 o;
#pragma unroll
  for (int j = 0; j < 8; ++j) o[j] = (__bf16)W[(k8 * 8 + j) * 1024 + v];
  *(bf16x8*)(P + (size_t)idx * 8) = o;
}

// ---------------- projections: pe = enc@We + be, pd = dec@Wd + bd --------------
__global__ __launch_bounds__(256)
void proj_mfma(const float* __restrict__ enc, const float* __restrict__ dec,
               const __bf16* __restrict__ Pen, const __bf16* __restrict__ Pde,
               const float* __restrict__ be, const float* __restrict__ bd,
               float* __restrict__ pe, float* __restrict__ pd)
{
  constexpr int BK = 128;
  __shared__ __align__(16) char As[2][64 * BK * 2];   // 32KB
  const int tid = threadIdx.x;
  const int lane = tid & 63;
  const int wid  = tid >> 6;        // 0..3
  const int l31  = lane & 31;
  const int lhi  = lane >> 5;

  int bi = blockIdx.x;
  const float* X; const __bf16* PW; const float* bias; float* P; int rt, ct;
  if (bi < 64) { X = enc; PW = Pen; bias = be; P = pe; rt = bi >> 2; ct = bi & 3; }
  else { int bj = bi - 64; X = dec; PW = Pde; bias = bd; P = pd; rt = bj >> 2; ct = bj & 3; }
  const int r0 = rt * 64;

  auto fillA = [&](int buf, int kc) {
#pragma unroll
    for (int i = 0; i < 4; ++i) {
      int tau = i * 256 + tid;
      int r = tau >> 4, g = tau & 15;
      int k = kc * BK + g * 8;
      const float4* x4 = (const float4*)(X + (r0 + r) * DK + k);
      float4 a0 = x4[0], a1 = x4[1];
      float xv[8] = {a0.x, a0.y, a0.z, a0.w, a1.x, a1.y, a1.z, a1.w};
      bf16x8 p;
#pragma unroll
      for (int q = 0; q < 8; ++q) p[q] = (__bf16)xv[q];
      *(bf16x8*)(&As[buf][r * (BK * 2) + ((g * 16) ^ ((r & 7) << 4))]) = p;
    }
  };

  f32x16 acc[2][2];
#pragma unroll
  for (int mi = 0; mi < 2; ++mi)
#pragma unroll
    for (int ni = 0; ni < 2; ++ni)
#pragma unroll
      for (int q = 0; q < 16; ++q) acc[mi][ni][q] = 0.f;

  fillA(0, 0);
  __syncthreads();
  const int colBase = ct * 256 + wid * 64 + l31;
  for (int kc = 0; kc < DK / BK; ++kc) {
    if (kc + 1 < DK / BK) fillA((kc + 1) & 1, kc + 1);
    const char* Ab = As[kc & 1];
#pragma unroll 2
    for (int ks = 0; ks < BK / 16; ++ks) {
      int k8 = (kc * 8 + ks) * 2 + lhi;
      bf16x8 bfr[2];
#pragma unroll
      for (int ni = 0; ni < 2; ++ni)
        bfr[ni] = *(const bf16x8*)(PW + ((size_t)k8 * VV + colBase + ni * 32) * 8);
      bf16x8 afr[2];
#pragma unroll
      for (int mi = 0; mi < 2; ++mi) {
        int ra = mi * 32 + l31;
        int kb = ks * 32 + lhi * 16;
        afr[mi] = *(const bf16x8*)(&Ab[ra * (BK * 2) + (kb ^ ((ra & 7) << 4))]);
      }
#pragma unroll
      for (int mi = 0; mi < 2; ++mi)
#pragma unroll
        for (int ni = 0; ni < 2; ++ni)
          acc[mi][ni] = __builtin_amdgcn_mfma_f32_32x32x16_bf16(afr[mi], bfr[ni], acc[mi][ni], 0, 0, 0);
    }
    __syncthreads();
  }
  float bv[2];
#pragma unroll
  for (int ni = 0; ni < 2; ++ni) bv[ni] = bias[colBase + ni * 32];
#pragma unroll
  for (int mi = 0; mi < 2; ++mi)
#pragma unroll
    for (int j = 0; j < 16; ++j) {
      int row = r0 + mi * 32 + (j & 3) + 8 * (j >> 2) + 4 * lhi;
#pragma unroll
      for (int ni = 0; ni < 2; ++ni)
        P[row * VV + colBase + ni * 32] = acc[mi][ni][j] + bv[ni];
    }
}

// ------ main: per-(b,t) block; B via gload_lds pipeline; fused log-softmax -----
__global__ __launch_bounds__(512, 2)
void joint_main(const float* __restrict__ pe, const float* __restrict__ pd,
                const __bf16* __restrict__ pW, const float* __restrict__ bfc,
                const int* __restrict__ elens, const int* __restrict__ dlens,
                float* __restrict__ out)
{
  // B chunk = 4 k8-slices (32 k-values) x 1024 cols x 16B = 64KB, double-buffered.
  // A super = 64 rows x 64 k bf16 = 8KB, double-buffered (1 super = 2 chunks).
  __shared__ __align__(16) unsigned char Bb[2][65536];   // 128KB
  __shared__ __align__(16) unsigned char Ab[2][8192];    // 16KB
  __shared__ float pr[8][64];                            // 2KB
  __shared__ float lseS[64];

  const int blk = blockIdx.x;        // = b*T + t
  const int b = blk >> 8;
  const int t = blk & 255;
  const int tid = threadIdx.x;
  const int elen = elens[b], dlen = dlens[b];
  float* outBase = out + (size_t)blk * (UU * VV);

  if (t >= elen) {                   // whole 64x1024 tile masked -> zeros
    float4 z = {0.f, 0.f, 0.f, 0.f};
#pragma unroll 4
    for (int i = tid; i < UU * VV / 4; i += 512) ((float4*)outBase)[i] = z;
    return;
  }

  const int lane = tid & 63;
  const int wid  = tid >> 6;         // 0..7
  const int l31  = lane & 31;
  const int lhi  = lane >> 5;
  const int colLane = wid * 128 + l31;

  const float* peRow  = pe + (size_t)blk * FF;
  const float* pdBase = pd + (size_t)b * UU * FF;

  // ---- B staging: 8 gload_lds dwordx4 per wave per chunk (64KB total) ----
  auto stageB = [&](int kc, int bi) {
    const __bf16* gp0 = pW + (size_t)kc * 32768;         // 64KB per chunk
#pragma unroll
    for (int i = 0; i < 8; ++i) {
      int fbase = i * 512 + wid * 64;                    // wave-uniform frag base
      __builtin_amdgcn_global_load_lds(
        (const __attribute__((address_space(1))) void*)(gp0 + ((size_t)(fbase + lane)) * 8),
        (__attribute__((address_space(3))) void*)(&Bb[bi][fbase * 16]),
        16, 0, 0);
    }
  };

  // ---- A staging: issue-early (even iter) / commit-late (odd iter) ----
  float4 R0, R1, R2, R3;
  const int ar = tid >> 3;           // row 0..63
  const int akg = tid & 7;           // k-group of 8 within super
  auto issueA = [&](int s) {
    int k = s * 64 + akg * 8;
    const float4* e4 = (const float4*)(peRow + k);
    const float4* d4 = (const float4*)(pdBase + (size_t)ar * FF + k);
    R0 = e4[0]; R1 = e4[1]; R2 = d4[0]; R3 = d4[1];
  };
  auto commitA = [&](int s) {
    float hv[8] = {R0.x + R2.x, R0.y + R2.y, R0.z + R2.z, R0.w + R2.w,
                   R1.x + R3.x, R1.y + R3.y, R1.z + R3.z, R1.w + R3.w};
    bf16x8 p;
#pragma unroll
    for (int e = 0; e < 8; ++e) p[e] = (__bf16)fast_tanh(hv[e]);
    *(bf16x8*)(&Ab[s & 1][ar * 128 + ((akg ^ (ar & 7)) << 4)]) = p;
  };

  f32x16 acc[2][4];
#pragma unroll
  for (int mi = 0; mi < 2; ++mi)
#pragma unroll
    for (int ni = 0; ni < 4; ++ni)
#pragma unroll
      for (int q = 0; q < 16; ++q) acc[mi][ni][q] = 0.f;

  auto mstep = [&](const unsigned char* Bbuf, const unsigned char* Abuf, int kc, int j) {
    bf16x8 bfr[4];
    const int k8l = 2 * j + lhi;
#pragma unroll
    for (int ni = 0; ni < 4; ++ni)
      bfr[ni] = *(const bf16x8*)(Bbuf + ((size_t)((k8l << 10) + colLane + (ni << 5)) << 4));
    bf16x8 afr[2];
    const int kg = ((kc & 1) << 2) + (j << 1) + lhi;
#pragma unroll
    for (int mi = 0; mi < 2; ++mi) {
      int row = mi * 32 + l31;
      afr[mi] = *(const bf16x8*)(Abuf + row * 128 + ((kg ^ (row & 7)) << 4));
    }
#pragma unroll
    for (int mi = 0; mi < 2; ++mi)
#pragma unroll
      for (int ni = 0; ni < 4; ++ni)
        acc[mi][ni] = __builtin_amdgcn_mfma_f32_32x32x16_bf16(afr[mi], bfr[ni], acc[mi][ni], 0, 0, 0);
  };

  // ---- prologue: A0 (issue+commit), B0, A1 issue; publish B0+A0 ----
  issueA(0);
  commitA(0);                                  // compiler inserts exact vmcnt wait
  stageB(0, 0);
  issueA(1);
  asm volatile("s_waitcnt vmcnt(4)" ::: "memory");   // B0 done (A1's 4 loads younger)
  asm volatile("s_waitcnt lgkmcnt(0)" ::: "memory"); // A0 ds_writes drained
  __builtin_amdgcn_sched_barrier(0);
  __builtin_amdgcn_s_barrier();
  __builtin_amdgcn_sched_barrier(0);

  for (int kc = 0; kc < 32; ++kc) {
    if (kc < 31) stageB(kc + 1, (kc + 1) & 1);           // full-iter flight
    if (kc >= 2 && (kc & 1) == 0 && (kc / 2 + 1) <= 15) issueA(kc / 2 + 1);
    __builtin_amdgcn_sched_barrier(0);                   // pin issues early
    const unsigned char* Bbuf = Bb[kc & 1];
    const unsigned char* Abuf = Ab[(kc >> 1) & 1];
    __builtin_amdgcn_s_setprio(1);
    mstep(Bbuf, Abuf, kc, 0);
    mstep(Bbuf, Abuf, kc, 1);
    __builtin_amdgcn_s_setprio(0);
    if ((kc & 1) == 1 && ((kc + 1) / 2) <= 15) commitA((kc + 1) / 2);
    if (kc < 31) {
      // publish: drain B(kc+1) gloads (had ~full iter in flight) + own ds ops,
      // THEN barrier. Never drains mid-compute.
      asm volatile("s_waitcnt vmcnt(0)" ::: "memory");
      asm volatile("s_waitcnt lgkmcnt(0)" ::: "memory");
      __builtin_amdgcn_sched_barrier(0);
      __builtin_amdgcn_s_barrier();
      __builtin_amdgcn_sched_barrier(0);
    }
  }

  // ---- epilogue: bias + exp row-sums (max-free; |logit| < 33 so exp fits fp32) ----
  float bias[4];
#pragma unroll
  for (int ni = 0; ni < 4; ++ni) bias[ni] = bfc[colLane + ni * 32];

  float rsum[2][16];
#pragma unroll
  for (int mi = 0; mi < 2; ++mi)
#pragma unroll
    for (int j = 0; j < 16; ++j) {
      float s = 0.f;
#pragma unroll
      for (int ni = 0; ni < 4; ++ni) {
        float v = acc[mi][ni][j] + bias[ni];
        acc[mi][ni][j] = v;
        s += __expf(v);
      }
      rsum[mi][j] = s;
    }
#pragma unroll
  for (int s = 1; s < 32; s <<= 1) {
#pragma unroll
    for (int mi = 0; mi < 2; ++mi)
#pragma unroll
      for (int j = 0; j < 16; ++j)
        rsum[mi][j] += __shfl_xor(rsum[mi][j], s, 64);
  }
#pragma unroll
  for (int mi = 0; mi < 2; ++mi)
#pragma unroll
    for (int j = 0; j < 16; ++j)
      if (l31 == j) {
        int row = mi * 32 + (j & 3) + 8 * (j >> 2) + 4 * lhi;
        pr[wid][row] = rsum[mi][j];
      }
  __syncthreads();
  if (tid < 64) {
    float s = 0.f;
#pragma unroll
    for (int w = 0; w < 8; ++w) s += pr[w][tid];
    lseS[tid] = __logf(s);
  }
  __syncthreads();

#pragma unroll
  for (int mi = 0; mi < 2; ++mi)
#pragma unroll
    for (int j = 0; j < 16; ++j) {
      int row = mi * 32 + (j & 3) + 8 * (j >> 2) + 4 * lhi;
      float l = lseS[row];
      bool valid = row < dlen;
#pragma unroll
      for (int ni = 0; ni < 4; ++ni) {
        float v = valid ? (acc[mi][ni][j] - l) : 0.0f;
        outBase[(size_t)row * VV + colLane + ni * 32] = v;
      }
    }
}

extern "C" void kernel_launch(void* const* d_in, const int* in_sizes, int n_in,
                              void* d_out, int out_size, void* d_ws, size_t ws_size,
                              hipStream_t stream)
{
  const float* enc  = (const float*)d_in[0];
  const float* dec  = (const float*)d_in[1];
  const float* Wenc = (const float*)d_in[2];
  const float* benc = (const float*)d_in[3];
  const float* Wdec = (const float*)d_in[4];
  const float* bdec = (const float*)d_in[5];
  const float* Wfc  = (const float*)d_in[6];
  const float* bfc  = (const float*)d_in[7];
  const int* elens  = (const int*)d_in[8];
  const int* dlens  = (const int*)d_in[9];
  float* out = (float*)d_out;

  float* pe = (float*)d_ws;                       // 1024*1024 f32
  float* pd = pe + 1024 * 1024;                   // 256*1024 f32
  __bf16* Pfc = (__bf16*)(pd + 256 * 1024);       // 1024*1024 bf16
  __bf16* Pen = Pfc + 1024 * 1024;                // 512*1024 bf16
  __bf16* Pde = Pen + 512 * 1024;                 // 512*1024 bf16

  pack_w<<<1024, 256, 0, stream>>>(Wfc, Wenc, Wdec, Pfc, Pen, Pde);
  proj_mfma<<<80, 256, 0, stream>>>(enc, dec, Pen, Pde, benc, bdec, pe, pd);
  joint_main<<<1024, 512, 0, stream>>>(pe, pd, Pfc, bfc, elens, dlens, out);
}

// Round 6
// 240.448 us; speedup vs baseline: 1.0893x; 1.0893x over previous
//
#include <hip/hip_runtime.h>
#include <hip/hip_bf16.h>

// JointNet: logp = log_softmax(tanh(enc@We + b_e (+) dec@Wd + b_d) @ Wfc + b_fc), masked.
// B=4 T=256 U=64 V=1024 F=1024 K_proj=512.
// R6 design: BM=64/BN=1024 forced; 1 block/CU, 2 waves/SIMD. B-feed is WAVE-PRIVATE:
// each wave stages its own 128-col slice of the next 32-k chunk via global_load_lds
// (8 x 16B issues) and syncs with counted s_waitcnt vmcnt(12/8/0) — NO barrier, NO
// vmcnt(0) in the steady loop. Barriers (lgkm-only) exist solely for the shared A-tile
// (tanh(pe+pd)), once per 64-k super = 16 total. A is frag-major with row^kg XOR
// (conflict-free read+write). MFMA floor 55us; B L2 stream ~36TB/s -> L2-co-bound.

#define TT 256
#define UU 64
#define VV 1024
#define FF 1024
#define DK 512

typedef __bf16 bf16x8 __attribute__((ext_vector_type(8)));
typedef float  f32x16 __attribute__((ext_vector_type(16)));

__device__ __forceinline__ float fast_tanh(float x) {
  float ax = __builtin_fabsf(x);
  float e  = __expf(-2.0f * ax);
  float r  = (1.0f - e) * __builtin_amdgcn_rcpf(1.0f + e);
  return __builtin_copysignf(r, x);
}

// ---------------- pack: W fp32 [K][1024] -> bf16 [K/8][1024][8] ----------------
__global__ __launch_bounds__(256)
void pack_w(const float* __restrict__ Wfc, const float* __restrict__ Wenc,
            const float* __restrict__ Wdec,
            __bf16* __restrict__ Pfc, __bf16* __restrict__ Pen, __bf16* __restrict__ Pde)
{
  int bi = blockIdx.x;
  const float* W; __bf16* P; int base;
  if (bi < 512)      { W = Wfc;  P = Pfc; base = bi; }
  else if (bi < 768) { W = Wenc; P = Pen; base = bi - 512; }
  else               { W = Wdec; P = Pde; base = bi - 768; }
  int idx = base * 256 + threadIdx.x;     // idx = k8*1024 + v
  int k8 = idx >> 10, v = idx & 1023;
  bf16x8 o;
#pragma unroll
  for (int j = 0; j < 8; ++j) o[j] = (__bf16)W[(k8 * 8 + j) * 1024 + v];
  *(bf16x8*)(P + (size_t)idx * 8) = o;
}

// ---------------- projections: pe = enc@We + be, pd = dec@Wd + bd --------------
__global__ __launch_bounds__(256)
void proj_mfma(const float* __restrict__ enc, const float* __restrict__ dec,
               const __bf16* __restrict__ Pen, const __bf16* __restrict__ Pde,
               const float* __restrict__ be, const float* __restrict__ bd,
               float* __restrict__ pe, float* __restrict__ pd)
{
  constexpr int BK = 128;
  __shared__ __align__(16) char As[2][64 * BK * 2];   // 32KB
  const int tid = threadIdx.x;
  const int lane = tid & 63;
  const int wid  = tid >> 6;        // 0..3
  const int l31  = lane & 31;
  const int lhi  = lane >> 5;

  int bi = blockIdx.x;
  const float* X; const __bf16* PW; const float* bias; float* P; int rt, ct;
  if (bi < 64) { X = enc; PW = Pen; bias = be; P = pe; rt = bi >> 2; ct = bi & 3; }
  else { int bj = bi - 64; X = dec; PW = Pde; bias = bd; P = pd; rt = bj >> 2; ct = bj & 3; }
  const int r0 = rt * 64;

  auto fillA = [&](int buf, int kc) {
#pragma unroll
    for (int i = 0; i < 4; ++i) {
      int tau = i * 256 + tid;
      int r = tau >> 4, g = tau & 15;
      int k = kc * BK + g * 8;
      const float4* x4 = (const float4*)(X + (r0 + r) * DK + k);
      float4 a0 = x4[0], a1 = x4[1];
      float xv[8] = {a0.x, a0.y, a0.z, a0.w, a1.x, a1.y, a1.z, a1.w};
      bf16x8 p;
#pragma unroll
      for (int q = 0; q < 8; ++q) p[q] = (__bf16)xv[q];
      *(bf16x8*)(&As[buf][r * (BK * 2) + ((g * 16) ^ ((r & 7) << 4))]) = p;
    }
  };

  f32x16 acc[2][2];
#pragma unroll
  for (int mi = 0; mi < 2; ++mi)
#pragma unroll
    for (int ni = 0; ni < 2; ++ni)
#pragma unroll
      for (int q = 0; q < 16; ++q) acc[mi][ni][q] = 0.f;

  fillA(0, 0);
  __syncthreads();
  const int colBase = ct * 256 + wid * 64 + l31;
  for (int kc = 0; kc < DK / BK; ++kc) {
    if (kc + 1 < DK / BK) fillA((kc + 1) & 1, kc + 1);
    const char* Ab = As[kc & 1];
#pragma unroll 2
    for (int ks = 0; ks < BK / 16; ++ks) {
      int k8 = (kc * 8 + ks) * 2 + lhi;
      bf16x8 bfr[2];
#pragma unroll
      for (int ni = 0; ni < 2; ++ni)
        bfr[ni] = *(const bf16x8*)(PW + ((size_t)k8 * VV + colBase + ni * 32) * 8);
      bf16x8 afr[2];
#pragma unroll
      for (int mi = 0; mi < 2; ++mi) {
        int ra = mi * 32 + l31;
        int kb = ks * 32 + lhi * 16;
        afr[mi] = *(const bf16x8*)(&Ab[ra * (BK * 2) + (kb ^ ((ra & 7) << 4))]);
      }
#pragma unroll
      for (int mi = 0; mi < 2; ++mi)
#pragma unroll
        for (int ni = 0; ni < 2; ++ni)
          acc[mi][ni] = __builtin_amdgcn_mfma_f32_32x32x16_bf16(afr[mi], bfr[ni], acc[mi][ni], 0, 0, 0);
    }
    __syncthreads();
  }
  float bv[2];
#pragma unroll
  for (int ni = 0; ni < 2; ++ni) bv[ni] = bias[colBase + ni * 32];
#pragma unroll
  for (int mi = 0; mi < 2; ++mi)
#pragma unroll
    for (int j = 0; j < 16; ++j) {
      int row = r0 + mi * 32 + (j & 3) + 8 * (j >> 2) + 4 * lhi;
#pragma unroll
      for (int ni = 0; ni < 2; ++ni)
        P[row * VV + colBase + ni * 32] = acc[mi][ni][j] + bv[ni];
    }
}

// ---- main: per-(b,t) block; wave-private B pipeline (counted vmcnt, no barrier);
// ---- shared A-super (barrier per 64k, lgkm-only); fused max-free log-softmax ----
__global__ __launch_bounds__(512, 2)
void joint_main(const float* __restrict__ pe, const float* __restrict__ pd,
                const __bf16* __restrict__ pW, const float* __restrict__ bfc,
                const int* __restrict__ elens, const int* __restrict__ dlens,
                float* __restrict__ out)
{
  // B chunk: 32 k (4 k8-slices) x 1024 cols x 16B-frag = 64KB, double-buffered.
  // A super: 64 k (8 kg) x 64 rows, frag-major [kg][row^kg] = 8KB, double-buffered.
  __shared__ __align__(16) unsigned char Bb[2][65536];   // 128KB
  __shared__ __align__(16) unsigned char Abuf[2][8192];  // 16KB
  __shared__ float pr[8][64];                            // 2KB
  __shared__ float lseS[64];

  const int blk = blockIdx.x;        // = b*T + t
  const int b = blk >> 8;
  const int t = blk & 255;
  const int tid = threadIdx.x;
  const int elen = elens[b], dlen = dlens[b];
  float* outBase = out + (size_t)blk * (UU * VV);

  if (t >= elen) {                   // whole 64x1024 tile masked -> zeros
    float4 z = {0.f, 0.f, 0.f, 0.f};
#pragma unroll 4
    for (int i = tid; i < UU * VV / 4; i += 512) ((float4*)outBase)[i] = z;
    return;
  }

  const int lane = tid & 63;
  const int wid  = tid >> 6;         // 0..7
  const int l31  = lane & 31;
  const int lhi  = lane >> 5;
  const int colLane = wid * 128 + l31;

  const float* peRow  = pe + (size_t)blk * FF;
  const float* pdBase = pd + (size_t)b * UU * FF;

  // ---- B staging: WAVE-PRIVATE. Wave wid stages cols [wid*128, wid*128+128)
  // of chunk kc (4 k8-slices): 8 x global_load_lds 16B. Sync = counted vmcnt.
  auto stageB = [&](int kc, int bi) {
    const __bf16* gp0 = pW + (size_t)kc * 32768;
#pragma unroll
    for (int i = 0; i < 8; ++i) {
      int fb = (i >> 1) * 1024 + wid * 128 + (i & 1) * 64;   // wave-uniform frag base
      __builtin_amdgcn_global_load_lds(
        (const __attribute__((address_space(1))) void*)(gp0 + ((size_t)fb + lane) * 8),
        (__attribute__((address_space(3))) void*)(&Bb[bi][(size_t)fb * 16]),
        16, 0, 0);
    }
  };

  // ---- A staging: issue-early / commit-late; frag-major [kg][row^kg] ----
  float4 R0, R1, R2, R3;
  const int ar  = tid >> 3;          // row 0..63
  const int akg = tid & 7;           // kg 0..7 within super
  auto issueA = [&](int s) {
    int k = s * 64 + akg * 8;
    const float4* e4 = (const float4*)(peRow + k);
    const float4* d4 = (const float4*)(pdBase + (size_t)ar * FF + k);
    R0 = e4[0]; R1 = e4[1]; R2 = d4[0]; R3 = d4[1];
  };
  auto commitA = [&](int s) {
    float hv[8] = {R0.x + R2.x, R0.y + R2.y, R0.z + R2.z, R0.w + R2.w,
                   R1.x + R3.x, R1.y + R3.y, R1.z + R3.z, R1.w + R3.w};
    bf16x8 p;
#pragma unroll
    for (int e = 0; e < 8; ++e) p[e] = (__bf16)fast_tanh(hv[e]);
    *(bf16x8*)(&Abuf[s & 1][((akg << 6) + (ar ^ akg)) << 4]) = p;
  };

  f32x16 acc[2][4];
#pragma unroll
  for (int mi = 0; mi < 2; ++mi)
#pragma unroll
    for (int ni = 0; ni < 4; ++ni)
#pragma unroll
      for (int q = 0; q < 16; ++q) acc[mi][ni][q] = 0.f;

  auto mstep = [&](const unsigned char* Bp, const unsigned char* Ap, int kc, int j) {
    const int k8l = (j << 1) + lhi;                      // 0..3 within chunk
    bf16x8 bfr[4];
#pragma unroll
    for (int ni = 0; ni < 4; ++ni)
      bfr[ni] = *(const bf16x8*)(Bp + ((size_t)((k8l << 10) + colLane + (ni << 5)) << 4));
    const int kg = ((kc & 1) << 2) + (j << 1) + lhi;     // 0..7 within super
    bf16x8 afr[2];
#pragma unroll
    for (int mi = 0; mi < 2; ++mi) {
      int row = mi * 32 + l31;
      afr[mi] = *(const bf16x8*)(Ap + (((kg << 6) + (row ^ kg)) << 4));
    }
#pragma unroll
    for (int mi = 0; mi < 2; ++mi)
#pragma unroll
      for (int ni = 0; ni < 4; ++ni)
        acc[mi][ni] = __builtin_amdgcn_mfma_f32_32x32x16_bf16(afr[mi], bfr[ni], acc[mi][ni], 0, 0, 0);
  };

  // ---- prologue: A0 staged+published; B0 in flight across the barrier ----
  issueA(0);
  commitA(0);                       // compiler inserts exact vmcnt wait for R0..R3
  stageB(0, 0);                     // +8 vm, rides through barrier
  asm volatile("s_waitcnt lgkmcnt(0)" ::: "memory");
  __builtin_amdgcn_sched_barrier(0);
  __builtin_amdgcn_s_barrier();
  __builtin_amdgcn_sched_barrier(0);

  // ---- main loop: 16 supers x 2 chunk-iters; no vmcnt(0), 1 lgkm-barrier/super ----
#pragma unroll 1
  for (int s = 0; s < 15; ++s) {
    const int kc0 = 2 * s;
    // even iter: consume B(kc0) from Bb[0]
    stageB(kc0 + 1, 1);                                  // +8
    issueA(s + 1);                                       // +4
    asm volatile("s_waitcnt vmcnt(12)" ::: "memory");    // drain B(kc0)
    __builtin_amdgcn_sched_barrier(0);
    __builtin_amdgcn_s_setprio(1);
    mstep(Bb[0], Abuf[s & 1], kc0, 0);
    mstep(Bb[0], Abuf[s & 1], kc0, 1);
    __builtin_amdgcn_s_setprio(0);
    // odd iter: consume B(kc0+1) from Bb[1]
    stageB(kc0 + 2, 0);                                  // +8
    asm volatile("s_waitcnt vmcnt(12)" ::: "memory");    // drain B(kc0+1)
    __builtin_amdgcn_sched_barrier(0);
    __builtin_amdgcn_s_setprio(1);
    mstep(Bb[1], Abuf[s & 1], kc0 + 1, 0);
    mstep(Bb[1], Abuf[s & 1], kc0 + 1, 1);
    __builtin_amdgcn_s_setprio(0);
    commitA(s + 1);                 // compiler waits A regs (vmcnt(8): B younger)
    asm volatile("s_waitcnt lgkmcnt(0)" ::: "memory");   // publish A(s+1); B rides
    __builtin_amdgcn_sched_barrier(0);
    __builtin_amdgcn_s_barrier();
    __builtin_amdgcn_sched_barrier(0);
  }
  { // ---- last super s=15: kc 30,31 ----
    stageB(31, 1);
    asm volatile("s_waitcnt vmcnt(8)" ::: "memory");     // drain B(30)
    __builtin_amdgcn_sched_barrier(0);
    __builtin_amdgcn_s_setprio(1);
    mstep(Bb[0], Abuf[1], 30, 0);
    mstep(Bb[0], Abuf[1], 30, 1);
    __builtin_amdgcn_s_setprio(0);
    asm volatile("s_waitcnt vmcnt(0)" ::: "memory");     // drain B(31)
    __builtin_amdgcn_sched_barrier(0);
    __builtin_amdgcn_s_setprio(1);
    mstep(Bb[1], Abuf[1], 31, 0);
    mstep(Bb[1], Abuf[1], 31, 1);
    __builtin_amdgcn_s_setprio(0);
  }

  // ---- epilogue: bias + exp row-sums (max-free; |logit| < 33 so exp fits fp32) ----
  float bias[4];
#pragma unroll
  for (int ni = 0; ni < 4; ++ni) bias[ni] = bfc[colLane + ni * 32];

  float rsum[2][16];
#pragma unroll
  for (int mi = 0; mi < 2; ++mi)
#pragma unroll
    for (int j = 0; j < 16; ++j) {
      float s = 0.f;
#pragma unroll
      for (int ni = 0; ni < 4; ++ni) {
        float v = acc[mi][ni][j] + bias[ni];
        acc[mi][ni][j] = v;
        s += __expf(v);
      }
      rsum[mi][j] = s;
    }
#pragma unroll
  for (int s = 1; s < 32; s <<= 1) {
#pragma unroll
    for (int mi = 0; mi < 2; ++mi)
#pragma unroll
      for (int j = 0; j < 16; ++j)
        rsum[mi][j] += __shfl_xor(rsum[mi][j], s, 64);
  }
#pragma unroll
  for (int mi = 0; mi < 2; ++mi)
#pragma unroll
    for (int j = 0; j < 16; ++j)
      if (l31 == j) {
        int row = mi * 32 + (j & 3) + 8 * (j >> 2) + 4 * lhi;
        pr[wid][row] = rsum[mi][j];
      }
  __syncthreads();
  if (tid < 64) {
    float s = 0.f;
#pragma unroll
    for (int w = 0; w < 8; ++w) s += pr[w][tid];
    lseS[tid] = __logf(s);
  }
  __syncthreads();

#pragma unroll
  for (int mi = 0; mi < 2; ++mi)
#pragma unroll
    for (int j = 0; j < 16; ++j) {
      int row = mi * 32 + (j & 3) + 8 * (j >> 2) + 4 * lhi;
      float l = lseS[row];
      bool valid = row < dlen;
#pragma unroll
      for (int ni = 0; ni < 4; ++ni) {
        float v = valid ? (acc[mi][ni][j] - l) : 0.0f;
        outBase[(size_t)row * VV + colLane + ni * 32] = v;
      }
    }
}

extern "C" void kernel_launch(void* const* d_in, const int* in_sizes, int n_in,
                              void* d_out, int out_size, void* d_ws, size_t ws_size,
                              hipStream_t stream)
{
  const float* enc  = (const float*)d_in[0];
  const float* dec  = (const float*)d_in[1];
  const float* Wenc = (const float*)d_in[2];
  const float* benc = (const float*)d_in[3];
  const float* Wdec = (const float*)d_in[4];
  const float* bdec = (const float*)d_in[5];
  const float* Wfc  = (const float*)d_in[6];
  const float* bfc  = (const float*)d_in[7];
  const int* elens  = (const int*)d_in[8];
  const int* dlens  = (const int*)d_in[9];
  float* out = (float*)d_out;

  float* pe = (float*)d_ws;                       // 1024*1024 f32
  float* pd = pe + 1024 * 1024;                   // 256*1024 f32
  __bf16* Pfc = (__bf16*)(pd + 256 * 1024);       // 1024*1024 bf16
  __bf16* Pen = Pfc + 1024 * 1024;                // 512*1024 bf16
  __bf16* Pde = Pen + 512 * 1024;                 // 512*1024 bf16

  pack_w<<<1024, 256, 0, stream>>>(Wfc, Wenc, Wdec, Pfc, Pen, Pde);
  proj_mfma<<<80, 256, 0, stream>>>(enc, dec, Pen, Pde, benc, bdec, pe, pd);
  joint_main<<<1024, 512, 0, stream>>>(pe, pd, Pfc, bfc, elens, dlens, out);
}

// Round 7
// 231.176 us; speedup vs baseline: 1.1330x; 1.0401x over previous
//
#include <hip/hip_runtime.h>
#include <hip/hip_bf16.h>

// JointNet: logp = log_softmax(tanh(enc@We + b_e (+) dec@Wd + b_d) @ Wfc + b_fc), masked.
// B=4 T=256 U=64 V=1024 F=1024 K_proj=512.
// R6 postmortem: all schedules pin at ~250us, MfmaUtil ~17%, conflicts 0 -> effective
// B-feed ~14 B/cyc/CU, 4x under L2 fair share. Theory: CONVOY — all 1024 blocks walk
// W_fc in the same kc order, XCD CUs hammer the same L2 lines (no multicast).
// R7: per-block ROTATION of the K-super order (rot = blk & 15). Sync structure,
// vmcnt counts, wave-private B staging, lgkm-only A barriers — all unchanged from R6.

#define TT 256
#define UU 64
#define VV 1024
#define FF 1024
#define DK 512

typedef __bf16 bf16x8 __attribute__((ext_vector_type(8)));
typedef float  f32x16 __attribute__((ext_vector_type(16)));

__device__ __forceinline__ float fast_tanh(float x) {
  float ax = __builtin_fabsf(x);
  float e  = __expf(-2.0f * ax);
  float r  = (1.0f - e) * __builtin_amdgcn_rcpf(1.0f + e);
  return __builtin_copysignf(r, x);
}

// ---------------- pack: W fp32 [K][1024] -> bf16 [K/8][1024][8] ----------------
__global__ __launch_bounds__(256)
void pack_w(const float* __restrict__ Wfc, const float* __restrict__ Wenc,
            const float* __restrict__ Wdec,
            __bf16* __restrict__ Pfc, __bf16* __restrict__ Pen, __bf16* __restrict__ Pde)
{
  int bi = blockIdx.x;
  const float* W; __bf16* P; int base;
  if (bi < 512)      { W = Wfc;  P = Pfc; base = bi; }
  else if (bi < 768) { W = Wenc; P = Pen; base = bi - 512; }
  else               { W = Wdec; P = Pde; base = bi - 768; }
  int idx = base * 256 + threadIdx.x;     // idx = k8*1024 + v
  int k8 = idx >> 10, v = idx & 1023;
  bf16x8 o;
#pragma unroll
  for (int j = 0; j < 8; ++j) o[j] = (__bf16)W[(k8 * 8 + j) * 1024 + v];
  *(bf16x8*)(P + (size_t)idx * 8) = o;
}

// ---------------- projections: pe = enc@We + be, pd = dec@Wd + bd --------------
__global__ __launch_bounds__(256)
void proj_mfma(const float* __restrict__ enc, const float* __restrict__ dec,
               const __bf16* __restrict__ Pen, const __bf16* __restrict__ Pde,
               const float* __restrict__ be, const float* __restrict__ bd,
               float* __restrict__ pe, float* __restrict__ pd)
{
  constexpr int BK = 128;
  __shared__ __align__(16) char As[2][64 * BK * 2];   // 32KB
  const int tid = threadIdx.x;
  const int lane = tid & 63;
  const int wid  = tid >> 6;        // 0..3
  const int l31  = lane & 31;
  const int lhi  = lane >> 5;

  int bi = blockIdx.x;
  const float* X; const __bf16* PW; const float* bias; float* P; int rt, ct;
  if (bi < 64) { X = enc; PW = Pen; bias = be; P = pe; rt = bi >> 2; ct = bi & 3; }
  else { int bj = bi - 64; X = dec; PW = Pde; bias = bd; P = pd; rt = bj >> 2; ct = bj & 3; }
  const int r0 = rt * 64;

  auto fillA = [&](int buf, int kc) {
#pragma unroll
    for (int i = 0; i < 4; ++i) {
      int tau = i * 256 + tid;
      int r = tau >> 4, g = tau & 15;
      int k = kc * BK + g * 8;
      const float4* x4 = (const float4*)(X + (r0 + r) * DK + k);
      float4 a0 = x4[0], a1 = x4[1];
      float xv[8] = {a0.x, a0.y, a0.z, a0.w, a1.x, a1.y, a1.z, a1.w};
      bf16x8 p;
#pragma unroll
      for (int q = 0; q < 8; ++q) p[q] = (__bf16)xv[q];
      *(bf16x8*)(&As[buf][r * (BK * 2) + ((g * 16) ^ ((r & 7) << 4))]) = p;
    }
  };

  f32x16 acc[2][2];
#pragma unroll
  for (int mi = 0; mi < 2; ++mi)
#pragma unroll
    for (int ni = 0; ni < 2; ++ni)
#pragma unroll
      for (int q = 0; q < 16; ++q) acc[mi][ni][q] = 0.f;

  fillA(0, 0);
  __syncthreads();
  const int colBase = ct * 256 + wid * 64 + l31;
  for (int kc = 0; kc < DK / BK; ++kc) {
    if (kc + 1 < DK / BK) fillA((kc + 1) & 1, kc + 1);
    const char* Ab = As[kc & 1];
#pragma unroll 2
    for (int ks = 0; ks < BK / 16; ++ks) {
      int k8 = (kc * 8 + ks) * 2 + lhi;
      bf16x8 bfr[2];
#pragma unroll
      for (int ni = 0; ni < 2; ++ni)
        bfr[ni] = *(const bf16x8*)(PW + ((size_t)k8 * VV + colBase + ni * 32) * 8);
      bf16x8 afr[2];
#pragma unroll
      for (int mi = 0; mi < 2; ++mi) {
        int ra = mi * 32 + l31;
        int kb = ks * 32 + lhi * 16;
        afr[mi] = *(const bf16x8*)(&Ab[ra * (BK * 2) + (kb ^ ((ra & 7) << 4))]);
      }
#pragma unroll
      for (int mi = 0; mi < 2; ++mi)
#pragma unroll
        for (int ni = 0; ni < 2; ++ni)
          acc[mi][ni] = __builtin_amdgcn_mfma_f32_32x32x16_bf16(afr[mi], bfr[ni], acc[mi][ni], 0, 0, 0);
    }
    __syncthreads();
  }
  float bv[2];
#pragma unroll
  for (int ni = 0; ni < 2; ++ni) bv[ni] = bias[colBase + ni * 32];
#pragma unroll
  for (int mi = 0; mi < 2; ++mi)
#pragma unroll
    for (int j = 0; j < 16; ++j) {
      int row = r0 + mi * 32 + (j & 3) + 8 * (j >> 2) + 4 * lhi;
#pragma unroll
      for (int ni = 0; ni < 2; ++ni)
        P[row * VV + colBase + ni * 32] = acc[mi][ni][j] + bv[ni];
    }
}

// ---- main: per-(b,t) block; wave-private B pipeline (counted vmcnt, no barrier);
// ---- per-block ROTATED K order (convoy breaker); lgkm-only A barriers; fused softmax.
__global__ __launch_bounds__(512, 2)
void joint_main(const float* __restrict__ pe, const float* __restrict__ pd,
                const __bf16* __restrict__ pW, const float* __restrict__ bfc,
                const int* __restrict__ elens, const int* __restrict__ dlens,
                float* __restrict__ out)
{
  // B chunk: 32 k (4 k8-slices) x 1024 cols x 16B-frag = 64KB, double-buffered.
  // A super: 64 k (8 kg) x 64 rows, frag-major [kg][row^kg] = 8KB, double-buffered.
  __shared__ __align__(16) unsigned char Bb[2][65536];   // 128KB
  __shared__ __align__(16) unsigned char Abuf[2][8192];  // 16KB
  __shared__ float pr[8][64];                            // 2KB
  __shared__ float lseS[64];

  const int blk = blockIdx.x;        // = b*T + t
  const int b = blk >> 8;
  const int t = blk & 255;
  const int tid = threadIdx.x;
  const int elen = elens[b], dlen = dlens[b];
  float* outBase = out + (size_t)blk * (UU * VV);

  if (t >= elen) {                   // whole 64x1024 tile masked -> zeros
    float4 z = {0.f, 0.f, 0.f, 0.f};
#pragma unroll 4
    for (int i = tid; i < UU * VV / 4; i += 512) ((float4*)outBase)[i] = z;
    return;
  }

  const int lane = tid & 63;
  const int wid  = tid >> 6;         // 0..7
  const int l31  = lane & 31;
  const int lhi  = lane >> 5;
  const int colLane = wid * 128 + l31;
  const int rot  = blk & 15;         // per-block K-super rotation (convoy breaker)

  const float* peRow  = pe + (size_t)blk * FF;
  const float* pdBase = pd + (size_t)b * UU * FF;

  // ---- B staging: WAVE-PRIVATE. Wave wid stages cols [wid*128, wid*128+128)
  // of chunk kc (4 k8-slices): 8 x global_load_lds 16B. Sync = counted vmcnt.
  auto stageB = [&](int kc, int bi) {
    const __bf16* gp0 = pW + (size_t)kc * 32768;
#pragma unroll
    for (int i = 0; i < 8; ++i) {
      int fb = (i >> 1) * 1024 + wid * 128 + (i & 1) * 64;   // wave-uniform frag base
      __builtin_amdgcn_global_load_lds(
        (const __attribute__((address_space(1))) void*)(gp0 + ((size_t)fb + lane) * 8),
        (__attribute__((address_space(3))) void*)(&Bb[bi][(size_t)fb * 16]),
        16, 0, 0);
    }
  };

  // ---- A staging: issue-early / commit-late; frag-major [kg][row^kg] ----
  // issueA takes the PHYSICAL super (rotated); commitA takes loop parity.
  float4 R0, R1, R2, R3;
  const int ar  = tid >> 3;          // row 0..63
  const int akg = tid & 7;           // kg 0..7 within super
  auto issueA = [&](int sPhys) {
    int k = sPhys * 64 + akg * 8;
    const float4* e4 = (const float4*)(peRow + k);
    const float4* d4 = (const float4*)(pdBase + (size_t)ar * FF + k);
    R0 = e4[0]; R1 = e4[1]; R2 = d4[0]; R3 = d4[1];
  };
  auto commitA = [&](int par) {
    float hv[8] = {R0.x + R2.x, R0.y + R2.y, R0.z + R2.z, R0.w + R2.w,
                   R1.x + R3.x, R1.y + R3.y, R1.z + R3.z, R1.w + R3.w};
    bf16x8 p;
#pragma unroll
    for (int e = 0; e < 8; ++e) p[e] = (__bf16)fast_tanh(hv[e]);
    *(bf16x8*)(&Abuf[par & 1][((akg << 6) + (ar ^ akg)) << 4]) = p;
  };

  f32x16 acc[2][4];
#pragma unroll
  for (int mi = 0; mi < 2; ++mi)
#pragma unroll
    for (int ni = 0; ni < 4; ++ni)
#pragma unroll
      for (int q = 0; q < 16; ++q) acc[mi][ni][q] = 0.f;

  // half = chunk index within super (0: kg 0..3, 1: kg 4..7)
  auto mstep = [&](const unsigned char* Bp, const unsigned char* Ap, int half, int j) {
    const int k8l = (j << 1) + lhi;                      // 0..3 within chunk
    bf16x8 bfr[4];
#pragma unroll
    for (int ni = 0; ni < 4; ++ni)
      bfr[ni] = *(const bf16x8*)(Bp + ((size_t)((k8l << 10) + colLane + (ni << 5)) << 4));
    const int kg = (half << 2) + (j << 1) + lhi;         // 0..7 within super
    bf16x8 afr[2];
#pragma unroll
    for (int mi = 0; mi < 2; ++mi) {
      int row = mi * 32 + l31;
      afr[mi] = *(const bf16x8*)(Ap + (((kg << 6) + (row ^ kg)) << 4));
    }
#pragma unroll
    for (int mi = 0; mi < 2; ++mi)
#pragma unroll
      for (int ni = 0; ni < 4; ++ni)
        acc[mi][ni] = __builtin_amdgcn_mfma_f32_32x32x16_bf16(afr[mi], bfr[ni], acc[mi][ni], 0, 0, 0);
  };

  // ---- prologue: A(rot) staged+published; B(2*rot) in flight across the barrier ----
  issueA(rot);
  commitA(0);                       // compiler inserts exact vmcnt wait for R0..R3
  stageB(2 * rot, 0);               // +8 vm, rides through barrier
  asm volatile("s_waitcnt lgkmcnt(0)" ::: "memory");
  __builtin_amdgcn_sched_barrier(0);
  __builtin_amdgcn_s_barrier();
  __builtin_amdgcn_sched_barrier(0);

  // ---- main loop: 16 supers (rotated order) x 2 chunk-iters; counted vmcnt only ----
#pragma unroll 1
  for (int s = 0; s < 16; ++s) {
    const int se  = (s + rot) & 15;          // physical super
    const int c1  = se * 2 + 1;
    const bool more = (s < 15);
    const int seN = (s + 1 + rot) & 15;      // next physical super
    // even iter: consume chunk c0 = 2*se from Bb[0]
    stageB(c1, 1);                                        // +8
    if (more) {
      issueA(seN);                                        // +4
      asm volatile("s_waitcnt vmcnt(12)" ::: "memory");   // drain c0 (out was 20)
    } else {
      asm volatile("s_waitcnt vmcnt(8)" ::: "memory");    // drain c0 (out was 16)
    }
    __builtin_amdgcn_sched_barrier(0);
    __builtin_amdgcn_s_setprio(1);
    mstep(Bb[0], Abuf[s & 1], 0, 0);
    mstep(Bb[0], Abuf[s & 1], 0, 1);
    __builtin_amdgcn_s_setprio(0);
    // odd iter: consume chunk c1 from Bb[1]
    if (more) {
      stageB(2 * seN, 0);                                 // +8
      asm volatile("s_waitcnt vmcnt(12)" ::: "memory");   // drain c1 (out was 20)
    } else {
      asm volatile("s_waitcnt vmcnt(0)" ::: "memory");    // drain c1 (out was 8)
    }
    __builtin_amdgcn_sched_barrier(0);
    __builtin_amdgcn_s_setprio(1);
    mstep(Bb[1], Abuf[s & 1], 1, 0);
    mstep(Bb[1], Abuf[s & 1], 1, 1);
    __builtin_amdgcn_s_setprio(0);
    if (more) {
      commitA((s + 1) & 1);         // compiler waits A regs (B loads are younger)
      asm volatile("s_waitcnt lgkmcnt(0)" ::: "memory");  // publish A; B rides through
      __builtin_amdgcn_sched_barrier(0);
      __builtin_amdgcn_s_barrier();
      __builtin_amdgcn_sched_barrier(0);
    }
  }

  // ---- epilogue: bias + exp row-sums (max-free; |logit| < 33 so exp fits fp32) ----
  float bias[4];
#pragma unroll
  for (int ni = 0; ni < 4; ++ni) bias[ni] = bfc[colLane + ni * 32];

  float rsum[2][16];
#pragma unroll
  for (int mi = 0; mi < 2; ++mi)
#pragma unroll
    for (int j = 0; j < 16; ++j) {
      float s = 0.f;
#pragma unroll
      for (int ni = 0; ni < 4; ++ni) {
        float v = acc[mi][ni][j] + bias[ni];
        acc[mi][ni][j] = v;
        s += __expf(v);
      }
      rsum[mi][j] = s;
    }
#pragma unroll
  for (int s = 1; s < 32; s <<= 1) {
#pragma unroll
    for (int mi = 0; mi < 2; ++mi)
#pragma unroll
      for (int j = 0; j < 16; ++j)
        rsum[mi][j] += __shfl_xor(rsum[mi][j], s, 64);
  }
#pragma unroll
  for (int mi = 0; mi < 2; ++mi)
#pragma unroll
    for (int j = 0; j < 16; ++j)
      if (l31 == j) {
        int row = mi * 32 + (j & 3) + 8 * (j >> 2) + 4 * lhi;
        pr[wid][row] = rsum[mi][j];
      }
  __syncthreads();
  if (tid < 64) {
    float s = 0.f;
#pragma unroll
    for (int w = 0; w < 8; ++w) s += pr[w][tid];
    lseS[tid] = __logf(s);
  }
  __syncthreads();

#pragma unroll
  for (int mi = 0; mi < 2; ++mi)
#pragma unroll
    for (int j = 0; j < 16; ++j) {
      int row = mi * 32 + (j & 3) + 8 * (j >> 2) + 4 * lhi;
      float l = lseS[row];
      bool valid = row < dlen;
#pragma unroll
      for (int ni = 0; ni < 4; ++ni) {
        float v = valid ? (acc[mi][ni][j] - l) : 0.0f;
        outBase[(size_t)row * VV + colLane + ni * 32] = v;
      }
    }
}

extern "C" void kernel_launch(void* const* d_in, const int* in_sizes, int n_in,
                              void* d_out, int out_size, void* d_ws, size_t ws_size,
                              hipStream_t stream)
{
  const float* enc  = (const float*)d_in[0];
  const float* dec  = (const float*)d_in[1];
  const float* Wenc = (const float*)d_in[2];
  const float* benc = (const float*)d_in[3];
  const float* Wdec = (const float*)d_in[4];
  const float* bdec = (const float*)d_in[5];
  const float* Wfc  = (const float*)d_in[6];
  const float* bfc  = (const float*)d_in[7];
  const int* elens  = (const int*)d_in[8];
  const int* dlens  = (const int*)d_in[9];
  float* out = (float*)d_out;

  float* pe = (float*)d_ws;                       // 1024*1024 f32
  float* pd = pe + 1024 * 1024;                   // 256*1024 f32
  __bf16* Pfc = (__bf16*)(pd + 256 * 1024);       // 1024*1024 bf16
  __bf16* Pen = Pfc + 1024 * 1024;                // 512*1024 bf16
  __bf16* Pde = Pen + 512 * 1024;                 // 512*1024 bf16

  pack_w<<<1024, 256, 0, stream>>>(Wfc, Wenc, Wdec, Pfc, Pen, Pde);
  proj_mfma<<<80, 256, 0, stream>>>(enc, dec, Pen, Pde, benc, bdec, pe, pd);
  joint_main<<<1024, 512, 0, stream>>>(pe, pd, Pfc, bfc, elens, dlens, out);
}